// Round 9
// baseline (277.139 us; speedup 1.0000x reference)
//
#include <hip/hip_runtime.h>
#include <hip/hip_bf16.h>

typedef unsigned short u16;
typedef short bf16x8 __attribute__((ext_vector_type(8)));
typedef float f32x4 __attribute__((ext_vector_type(4)));
typedef float f32x16 __attribute__((ext_vector_type(16)));

#define N_TOK 8192
#define DIM   1024
#define HID   2048
#define ADIM  128
#define SEQ   2048
#define LDP   2304   // row stride of hidP / WdQ (2048 + 256)

__device__ __forceinline__ u16 f2bf_bits(float f){
  unsigned u = __float_as_uint(f);
  unsigned r = (u + 0x7fffu + ((u >> 16) & 1u)) >> 16;
  return (u16)r;
}
__device__ __forceinline__ float bf2f(u16 v){ return __uint_as_float((unsigned)v << 16); }
__device__ __forceinline__ float siluf(float x){ return x / (1.f + __expf(-x)); }

__device__ __forceinline__ void gload16(const void* g, void* l){
  __builtin_amdgcn_global_load_lds((const __attribute__((address_space(1))) void*)g,
                                   (__attribute__((address_space(3))) void*)l, 16, 0, 0);
}

#define SB0() __builtin_amdgcn_sched_barrier(0)

// ================= 256^2 8-wave phased GEMM, 32x32x16 MFMA ==================
// Same 4-phase / counted-vmcnt schedule as r8 (ledger verified), but with
// mfma_f32_32x32x16_bf16: 2x FLOP per instruction for the same operand regs
// -> half the MFMA instruction count at identical LDS byte traffic.
// Wgu packed 32-row-interleaved: rows 64i..64i+32 = gate[32i..32i+32],
// rows 64i+32..64i+64 = up. Wave n-frag (32 cols) is pure gate or pure up;
// frag pair (0,1) = (gate, up) with matching lane&31 <-> same h column.
__global__ void __launch_bounds__(512, 2)
gemm_gu256(const u16* __restrict__ X, const u16* __restrict__ Wgu,
           const float* __restrict__ sumw, u16* __restrict__ hidP)
{
  extern __shared__ u16 lds[];
  const int tid = threadIdx.x, w = tid >> 6, lane = tid & 63;
  const int wm = w >> 2, wn = w & 3;
  // 2D-region XCD swizzle: each XCD owns an 8bm x 8bn region.
  const int xcd = blockIdx.x & 7, lloc = blockIdx.x >> 3;
  const int bm = (xcd >> 1) * 8 + (lloc & 7);
  const int bn = (xcd & 1) * 8 + (lloc >> 3);
  const long brow = (long)bm * 256, bcol = (long)bn * 256;
  const int r32 = lane & 31;          // frag row within 32-row tile
  const int khalf = lane >> 5;        // k sub-half select
  const int fkey = (lane >> 1) & 3;   // LDS read swizzle key ((r>>1)&3)
  const int srow = lane >> 2;
  const int sslot = (((lane & 3) ^ ((lane >> 3) & 3)) * 8);   // swizzled src slot

  f32x16 acc[4][2];
  #pragma unroll
  for (int m = 0; m < 4; m++)
    #pragma unroll
    for (int n = 0; n < 2; n++)
      #pragma unroll
      for (int i = 0; i < 16; i++) acc[m][n][i] = 0.f;

  auto stage = [&](const u16* __restrict__ gbase, long row0, int kt, int kh,
                   int p, int regoff) {
    #pragma unroll
    for (int i = 0; i < 2; i++) {
      const int r = (i * 8 + w) * 16 + srow;
      const u16* g = gbase + (row0 + r) * 1024 + kt * 64 + kh * 32 + sslot;
      u16* l = &lds[p * 32768 + regoff + kh * 8192 + (i * 8 + w) * 512];
      gload16(g, l);
    }
  };

  // frag read: row r in tile, k-elems (ks*16 + khalf*8 .. +8) of k-half kh,
  // slot swizzled by fkey (matches source permutation).
#define AFRAG(mf, kh, ks) (*(const bf16x8*)&lds[p*32768 + (kh)*8192 + (wm*128 + (mf)*32 + r32)*32 + ((((ks)*2 + khalf) ^ fkey)*8)])
#define BFRAG(nf, kh, ks) (*(const bf16x8*)&lds[p*32768 + 16384 + (kh)*8192 + (wn*64 + (nf)*32 + r32)*32 + ((((ks)*2 + khalf) ^ fkey)*8)])
#define MFMA32(a_, b_, c_) __builtin_amdgcn_mfma_f32_32x32x16_bf16(a_, b_, c_, 0, 0, 0)

  // prologue: tile 0 -> buf 0, order A0,B0,A1,B1; gate (A0,B0)
  stage(X, brow, 0, 0, 0, 0);
  stage(Wgu, bcol, 0, 0, 0, 16384);
  stage(X, brow, 0, 1, 0, 0);
  stage(Wgu, bcol, 0, 1, 0, 16384);
  asm volatile("s_waitcnt vmcnt(4)" ::: "memory");
  __builtin_amdgcn_s_barrier();

  for (int kt = 0; kt < 16; ++kt) {
    const int p = kt & 1, pn = p ^ 1;
    const int ktn = (kt < 15) ? kt + 1 : 15;
    bf16x8 a0, a1, a2, a3, b[2][2];

    // ---- P1 (kh0, m0-1): reads a(m0,ks0), b x4, a(m0,ks1), a(m1,ks0),
    //      a(m1,ks1); stage A0'; sliced lgkm + 2-MFMA groups
    a0 = AFRAG(0, 0, 0);
    b[0][0] = BFRAG(0, 0, 0); b[1][0] = BFRAG(1, 0, 0);
    b[0][1] = BFRAG(0, 0, 1); b[1][1] = BFRAG(1, 0, 1);
    SB0();
    a1 = AFRAG(0, 0, 1); SB0();
    a2 = AFRAG(1, 0, 0); SB0();
    a3 = AFRAG(1, 0, 1);
    stage(X, brow, ktn, 0, pn, 0);
    __builtin_amdgcn_s_barrier();
    asm volatile("s_waitcnt lgkmcnt(3)" ::: "memory"); SB0();
    __builtin_amdgcn_s_setprio(1);
    acc[0][0] = MFMA32(a0, b[0][0], acc[0][0]);
    acc[0][1] = MFMA32(a0, b[1][0], acc[0][1]);
    asm volatile("s_waitcnt lgkmcnt(2)" ::: "memory"); SB0();
    acc[0][0] = MFMA32(a1, b[0][1], acc[0][0]);
    acc[0][1] = MFMA32(a1, b[1][1], acc[0][1]);
    asm volatile("s_waitcnt lgkmcnt(1)" ::: "memory"); SB0();
    acc[1][0] = MFMA32(a2, b[0][0], acc[1][0]);
    acc[1][1] = MFMA32(a2, b[1][0], acc[1][1]);
    asm volatile("s_waitcnt lgkmcnt(0)" ::: "memory"); SB0();
    acc[1][0] = MFMA32(a3, b[0][1], acc[1][0]);
    acc[1][1] = MFMA32(a3, b[1][1], acc[1][1]);
    __builtin_amdgcn_s_setprio(0);
    __builtin_amdgcn_s_barrier();

    // ---- P2 (kh0, m2-3): reads a x4; stage B0'; vmcnt gate at end
    a0 = AFRAG(2, 0, 0); SB0();
    a1 = AFRAG(2, 0, 1); SB0();
    a2 = AFRAG(3, 0, 0); SB0();
    a3 = AFRAG(3, 0, 1);
    stage(Wgu, bcol, ktn, 0, pn, 16384);
    __builtin_amdgcn_s_barrier();
    asm volatile("s_waitcnt lgkmcnt(3)" ::: "memory"); SB0();
    __builtin_amdgcn_s_setprio(1);
    acc[2][0] = MFMA32(a0, b[0][0], acc[2][0]);
    acc[2][1] = MFMA32(a0, b[1][0], acc[2][1]);
    asm volatile("s_waitcnt lgkmcnt(2)" ::: "memory"); SB0();
    acc[2][0] = MFMA32(a1, b[0][1], acc[2][0]);
    acc[2][1] = MFMA32(a1, b[1][1], acc[2][1]);
    asm volatile("s_waitcnt lgkmcnt(1)" ::: "memory"); SB0();
    acc[3][0] = MFMA32(a2, b[0][0], acc[3][0]);
    acc[3][1] = MFMA32(a2, b[1][0], acc[3][1]);
    asm volatile("s_waitcnt lgkmcnt(0)" ::: "memory"); SB0();
    acc[3][0] = MFMA32(a3, b[0][1], acc[3][0]);
    acc[3][1] = MFMA32(a3, b[1][1], acc[3][1]);
    __builtin_amdgcn_s_setprio(0);
    asm volatile("s_waitcnt vmcnt(4)" ::: "memory");
    __builtin_amdgcn_s_barrier();

    // ---- P3 (kh1, m0-1): stage A1'
    a0 = AFRAG(0, 1, 0);
    b[0][0] = BFRAG(0, 1, 0); b[1][0] = BFRAG(1, 1, 0);
    b[0][1] = BFRAG(0, 1, 1); b[1][1] = BFRAG(1, 1, 1);
    SB0();
    a1 = AFRAG(0, 1, 1); SB0();
    a2 = AFRAG(1, 1, 0); SB0();
    a3 = AFRAG(1, 1, 1);
    stage(X, brow, ktn, 1, pn, 0);
    __builtin_amdgcn_s_barrier();
    asm volatile("s_waitcnt lgkmcnt(3)" ::: "memory"); SB0();
    __builtin_amdgcn_s_setprio(1);
    acc[0][0] = MFMA32(a0, b[0][0], acc[0][0]);
    acc[0][1] = MFMA32(a0, b[1][0], acc[0][1]);
    asm volatile("s_waitcnt lgkmcnt(2)" ::: "memory"); SB0();
    acc[0][0] = MFMA32(a1, b[0][1], acc[0][0]);
    acc[0][1] = MFMA32(a1, b[1][1], acc[0][1]);
    asm volatile("s_waitcnt lgkmcnt(1)" ::: "memory"); SB0();
    acc[1][0] = MFMA32(a2, b[0][0], acc[1][0]);
    acc[1][1] = MFMA32(a2, b[1][0], acc[1][1]);
    asm volatile("s_waitcnt lgkmcnt(0)" ::: "memory"); SB0();
    acc[1][0] = MFMA32(a3, b[0][1], acc[1][0]);
    acc[1][1] = MFMA32(a3, b[1][1], acc[1][1]);
    __builtin_amdgcn_s_setprio(0);
    __builtin_amdgcn_s_barrier();

    // ---- P4 (kh1, m2-3): stage B1'; vmcnt gate at end
    a0 = AFRAG(2, 1, 0); SB0();
    a1 = AFRAG(2, 1, 1); SB0();
    a2 = AFRAG(3, 1, 0); SB0();
    a3 = AFRAG(3, 1, 1);
    stage(Wgu, bcol, ktn, 1, pn, 16384);
    __builtin_amdgcn_s_barrier();
    asm volatile("s_waitcnt lgkmcnt(3)" ::: "memory"); SB0();
    __builtin_amdgcn_s_setprio(1);
    acc[2][0] = MFMA32(a0, b[0][0], acc[2][0]);
    acc[2][1] = MFMA32(a0, b[1][0], acc[2][1]);
    asm volatile("s_waitcnt lgkmcnt(2)" ::: "memory"); SB0();
    acc[2][0] = MFMA32(a1, b[0][1], acc[2][0]);
    acc[2][1] = MFMA32(a1, b[1][1], acc[2][1]);
    asm volatile("s_waitcnt lgkmcnt(1)" ::: "memory"); SB0();
    acc[3][0] = MFMA32(a2, b[0][0], acc[3][0]);
    acc[3][1] = MFMA32(a2, b[1][0], acc[3][1]);
    asm volatile("s_waitcnt lgkmcnt(0)" ::: "memory"); SB0();
    acc[3][0] = MFMA32(a3, b[0][1], acc[3][0]);
    acc[3][1] = MFMA32(a3, b[1][1], acc[3][1]);
    __builtin_amdgcn_s_setprio(0);
    asm volatile("s_waitcnt vmcnt(4)" ::: "memory");
    __builtin_amdgcn_s_barrier();
  }
#undef AFRAG
#undef BFRAG
#undef MFMA32

  // epilogue: 32x32 C/D layout col=lane&31, row=(reg&3)+8*(reg>>2)+4*(lane>>5)
  #pragma unroll
  for (int mf = 0; mf < 4; mf++) {
    #pragma unroll
    for (int reg = 0; reg < 16; reg++) {
      const long r = brow + wm * 128 + mf * 32 + (reg & 3) + 8 * (reg >> 2) + 4 * khalf;
      const float sw = sumw[r];
      const float g = acc[mf][0][reg], u = acc[mf][1][reg];
      const int hcol = bn * 128 + wn * 32 + r32;
      hidP[r * LDP + hcol] = f2bf_bits(sw * (siluf(g) * u));
    }
  }
}

// ---------------- generic C = A @ B^T GEMM, 128x128 tile, BK=32 -------------
enum { EPI_BF16 = 0, EPI_SILU = 2 };

template<int EPI>
__global__ void __launch_bounds__(256, 2)
gemm_bt(const u16* __restrict__ Ag, const u16* __restrict__ Bg, int K, int lda, int ldb,
        long sAz, long sBz, long sOz, u16* __restrict__ bout, int ldo, int col0)
{
  __shared__ u16 lA[128 * 32];
  __shared__ u16 lB[128 * 32];
  const int tid = threadIdx.x, wave = tid >> 6, lane = tid & 63;
  const long brow = (long)blockIdx.y * 128, bcol = (long)blockIdx.x * 128;
  const u16* A = Ag + (long)blockIdx.z * sAz + brow * lda;
  const u16* B = Bg + (long)blockIdx.z * sBz + bcol * ldb;
  const int wr = (wave >> 1) * 64, wc = (wave & 1) * 64;

  f32x4 acc[4][4];
  #pragma unroll
  for (int m = 0; m < 4; m++)
    #pragma unroll
    for (int n = 0; n < 4; n++)
      #pragma unroll
      for (int i = 0; i < 4; i++) acc[m][n][i] = 0.f;

  const int sr = tid >> 2, sks = ((tid & 3) ^ ((tid >> 3) & 3)) * 8;
  const u16* gA = A + (long)sr * lda + sks;
  const u16* gB = B + (long)sr * ldb + sks;
  const long rA = (long)64 * lda, rB = (long)64 * ldb;
  u16* lA0 = &lA[wave * 512]; u16* lA1 = &lA[2048 + wave * 512];
  u16* lB0 = &lB[wave * 512]; u16* lB1 = &lB[2048 + wave * 512];
  const int frow = lane & 15;
  const int fks = ((lane >> 4) * 8) ^ (((lane >> 1) & 3) << 3);

  for (int kt = 0; kt < K; kt += 32) {
    gload16(gA, lA0); gload16(gA + rA, lA1);
    gload16(gB, lB0); gload16(gB + rB, lB1);
    gA += 32; gB += 32;
    asm volatile("s_waitcnt vmcnt(0)" ::: "memory");
    __syncthreads();
    bf16x8 af[4], bfv[4];
    #pragma unroll
    for (int m = 0; m < 4; m++) af[m] = *(const bf16x8*)&lA[(wr + m * 16 + frow) * 32 + fks];
    #pragma unroll
    for (int n = 0; n < 4; n++) bfv[n] = *(const bf16x8*)&lB[(wc + n * 16 + frow) * 32 + fks];
    #pragma unroll
    for (int m = 0; m < 4; m++)
      #pragma unroll
      for (int n = 0; n < 4; n++)
        acc[m][n] = __builtin_amdgcn_mfma_f32_16x16x32_bf16(af[m], bfv[n], acc[m][n], 0, 0, 0);
    __syncthreads();
  }

  const long r0 = brow + wr + ((lane >> 4) << 2);
  const long c0 = bcol + wc + (lane & 15);
  u16* O = bout + (long)blockIdx.z * sOz;
  #pragma unroll
  for (int m = 0; m < 4; m++) {
    #pragma unroll
    for (int i = 0; i < 4; i++) {
      long r = r0 + m * 16 + i;
      #pragma unroll
      for (int n = 0; n < 4; n++) {
        long c = c0 + n * 16;
        float v = acc[m][n][i];
        if constexpr (EPI == EPI_BF16) {
          O[r * ldo + col0 + c] = f2bf_bits(v);
        } else {
          v = fminf(5.f, fmaxf(-5.f, v));
          O[r * ldo + c] = f2bf_bits(siluf(v));
        }
      }
    }
  }
}

// ---------------- final out = hidP @ WdQ^T  (K=2304, f32 out) ---------------
__global__ void __launch_bounds__(256, 2)
gemm_f32(const u16* __restrict__ Ag, const u16* __restrict__ Bg,
         float* __restrict__ out)
{
  __shared__ u16 lA[128 * 32];
  __shared__ u16 lB[128 * 32];
  const int tid = threadIdx.x, wave = tid >> 6, lane = tid & 63;
  const long brow = (long)blockIdx.y * 128, bcol = (long)blockIdx.x * 128;
  const int wr = (wave >> 1) * 64, wc = (wave & 1) * 64;

  f32x4 acc[4][4];
  #pragma unroll
  for (int m = 0; m < 4; m++)
    #pragma unroll
    for (int n = 0; n < 4; n++)
      #pragma unroll
      for (int i = 0; i < 4; i++) acc[m][n][i] = 0.f;

  const int sr = tid >> 2, sks = ((tid & 3) ^ ((tid >> 3) & 3)) * 8;
  const u16* gA = Ag + brow * LDP + (long)sr * LDP + sks;
  const u16* gB = Bg + bcol * LDP + (long)sr * LDP + sks;
  const long rA = (long)64 * LDP, rB = (long)64 * LDP;
  u16* lA0 = &lA[wave * 512]; u16* lA1 = &lA[2048 + wave * 512];
  u16* lB0 = &lB[wave * 512]; u16* lB1 = &lB[2048 + wave * 512];
  const int frow = lane & 15;
  const int fks = ((lane >> 4) * 8) ^ (((lane >> 1) & 3) << 3);

  for (int kt = 0; kt < LDP; kt += 32) {
    gload16(gA, lA0); gload16(gA + rA, lA1);
    gload16(gB, lB0); gload16(gB + rB, lB1);
    gA += 32; gB += 32;
    asm volatile("s_waitcnt vmcnt(0)" ::: "memory");
    __syncthreads();
    bf16x8 af[4], bfv[4];
    #pragma unroll
    for (int m = 0; m < 4; m++) af[m] = *(const bf16x8*)&lA[(wr + m * 16 + frow) * 32 + fks];
    #pragma unroll
    for (int n = 0; n < 4; n++) bfv[n] = *(const bf16x8*)&lB[(wc + n * 16 + frow) * 32 + fks];
    #pragma unroll
    for (int m = 0; m < 4; m++)
      #pragma unroll
      for (int n = 0; n < 4; n++)
        acc[m][n] = __builtin_amdgcn_mfma_f32_16x16x32_bf16(af[m], bfv[n], acc[m][n], 0, 0, 0);
    __syncthreads();
  }

  const long r0 = brow + wr + ((lane >> 4) << 2);
  const long c0 = bcol + wc + (lane & 15);
  #pragma unroll
  for (int m = 0; m < 4; m++)
    #pragma unroll
    for (int i = 0; i < 4; i++) {
      long r = r0 + m * 16 + i;
      #pragma unroll
      for (int n = 0; n < 4; n++)
        out[r * DIM + c0 + n * 16] = acc[m][n][i];
    }
}

// ------------- split-K partial GEMM: 128 output cols, f32 partials ----------
__global__ void __launch_bounds__(256, 2)
gemm_split(const u16* __restrict__ Ag, const u16* __restrict__ Bg, int Ksub, int nsplit,
           int lda, int ldb, long sAz, long sBz, float* __restrict__ part)
{
  __shared__ u16 lA[128 * 32];
  __shared__ u16 lB[128 * 32];
  const int tid = threadIdx.x, wave = tid >> 6, lane = tid & 63;
  const int z = blockIdx.z, batch = z / nsplit, split = z % nsplit;
  const long brow = (long)blockIdx.y * 128;
  const int Mrows = gridDim.y * 128;
  const u16* A = Ag + (long)batch * sAz + brow * lda + (long)split * Ksub;
  const u16* B = Bg + (long)batch * sBz + (long)split * Ksub;
  const int wr = (wave >> 1) * 64, wc = (wave & 1) * 64;

  f32x4 acc[4][4];
  #pragma unroll
  for (int m = 0; m < 4; m++)
    #pragma unroll
    for (int n = 0; n < 4; n++)
      #pragma unroll
      for (int i = 0; i < 4; i++) acc[m][n][i] = 0.f;

  const int sr = tid >> 2, sks = ((tid & 3) ^ ((tid >> 3) & 3)) * 8;
  const u16* gA = A + (long)sr * lda + sks;
  const u16* gB = B + (long)sr * ldb + sks;
  const long rA = (long)64 * lda, rB = (long)64 * ldb;
  u16* lA0 = &lA[wave * 512]; u16* lA1 = &lA[2048 + wave * 512];
  u16* lB0 = &lB[wave * 512]; u16* lB1 = &lB[2048 + wave * 512];
  const int frow = lane & 15;
  const int fks = ((lane >> 4) * 8) ^ (((lane >> 1) & 3) << 3);

  for (int kt = 0; kt < Ksub; kt += 32) {
    gload16(gA, lA0); gload16(gA + rA, lA1);
    gload16(gB, lB0); gload16(gB + rB, lB1);
    gA += 32; gB += 32;
    asm volatile("s_waitcnt vmcnt(0)" ::: "memory");
    __syncthreads();
    bf16x8 af[4], bfv[4];
    #pragma unroll
    for (int m = 0; m < 4; m++) af[m] = *(const bf16x8*)&lA[(wr + m * 16 + frow) * 32 + fks];
    #pragma unroll
    for (int n = 0; n < 4; n++) bfv[n] = *(const bf16x8*)&lB[(wc + n * 16 + frow) * 32 + fks];
    #pragma unroll
    for (int m = 0; m < 4; m++)
      #pragma unroll
      for (int n = 0; n < 4; n++)
        acc[m][n] = __builtin_amdgcn_mfma_f32_16x16x32_bf16(af[m], bfv[n], acc[m][n], 0, 0, 0);
    __syncthreads();
  }

  float* po = part + (long)z * Mrows * 128;
  const long rr = brow + wr + ((lane >> 4) << 2);
  const int cc = wc + (lane & 15);
  #pragma unroll
  for (int m = 0; m < 4; m++)
    #pragma unroll
    for (int i = 0; i < 4; i++) {
      long r = rr + m * 16 + i;
      #pragma unroll
      for (int n = 0; n < 4; n++)
        po[r * 128 + cc + n * 16] = acc[m][n][i];
    }
}

// ------ merged M1/M2 prep split GEMM: z<4 -> Wd@Wa^T, z>=4 -> Wo@We^T -------
__global__ void __launch_bounds__(256, 2)
gemm_split_q(const u16* __restrict__ A0, const u16* __restrict__ B0, int lda0,
             const u16* __restrict__ A1, const u16* __restrict__ B1, int lda1,
             float* __restrict__ part)
{
  __shared__ u16 lA[128 * 32];
  __shared__ u16 lB[128 * 32];
  const int tid = threadIdx.x, wave = tid >> 6, lane = tid & 63;
  const int z = blockIdx.z, sel = z >> 2, split = z & 3;
  const long brow = (long)blockIdx.y * 128;
  const int lda = sel ? lda1 : lda0;
  const u16* A = (sel ? A1 : A0) + brow * lda + (long)split * 512;
  const u16* B = (sel ? B1 : B0) + (long)split * 512;

  const int wr = (wave >> 1) * 64, wc = (wave & 1) * 64;
  f32x4 acc[4][4];
  #pragma unroll
  for (int m = 0; m < 4; m++)
    #pragma unroll
    for (int n = 0; n < 4; n++)
      #pragma unroll
      for (int i = 0; i < 4; i++) acc[m][n][i] = 0.f;

  const int sr = tid >> 2, sks = ((tid & 3) ^ ((tid >> 3) & 3)) * 8;
  const u16* gA = A + (long)sr * lda + sks;
  const u16* gB = B + (long)sr * HID + sks;
  const long rA = (long)64 * lda, rB = (long)64 * HID;
  u16* lA0 = &lA[wave * 512]; u16* lA1 = &lA[2048 + wave * 512];
  u16* lB0 = &lB[wave * 512]; u16* lB1 = &lB[2048 + wave * 512];
  const int frow = lane & 15;
  const int fks = ((lane >> 4) * 8) ^ (((lane >> 1) & 3) << 3);

  for (int kt = 0; kt < 512; kt += 32) {
    gload16(gA, lA0); gload16(gA + rA, lA1);
    gload16(gB, lB0); gload16(gB + rB, lB1);
    gA += 32; gB += 32;
    asm volatile("s_waitcnt vmcnt(0)" ::: "memory");
    __syncthreads();
    bf16x8 af[4], bfv[4];
    #pragma unroll
    for (int m = 0; m < 4; m++) af[m] = *(const bf16x8*)&lA[(wr + m * 16 + frow) * 32 + fks];
    #pragma unroll
    for (int n = 0; n < 4; n++) bfv[n] = *(const bf16x8*)&lB[(wc + n * 16 + frow) * 32 + fks];
    #pragma unroll
    for (int m = 0; m < 4; m++)
      #pragma unroll
      for (int n = 0; n < 4; n++)
        acc[m][n] = __builtin_amdgcn_mfma_f32_16x16x32_bf16(af[m], bfv[n], acc[m][n], 0, 0, 0);
    __syncthreads();
  }

  float* po = part + (long)z * 131072;
  const long rr = brow + wr + ((lane >> 4) << 2);
  const int cc = wc + (lane & 15);
  #pragma unroll
  for (int m = 0; m < 4; m++)
    #pragma unroll
    for (int i = 0; i < 4; i++) {
      long r = rr + m * 16 + i;
      #pragma unroll
      for (int n = 0; n < 4; n++)
        po[r * 128 + cc + n * 16] = acc[m][n][i];
    }
}

// ======== merged prep: router (blocks 0-511) | wprep (512-4863) |
//          cvt_t2 (4864-6911) ================================================
__global__ void __launch_bounds__(256)
prep_all(const float* __restrict__ x, const float* __restrict__ Wrg,
         const float* __restrict__ Wre, float* __restrict__ sumw,
         float* __restrict__ fwv, int* __restrict__ eidxv,
         float* __restrict__ stats, u16* __restrict__ xb,
         const float* __restrict__ Wg, const float* __restrict__ Wu,
         const float* __restrict__ Wd, const float* __restrict__ Wo,
         const float* __restrict__ Wpost, const float* __restrict__ Wpre,
         const float* __restrict__ Wead,
         u16* __restrict__ Wgu, u16* __restrict__ WdQ,
         u16* __restrict__ Wob, u16* __restrict__ Wpostb,
         u16* __restrict__ Wpreb, u16* __restrict__ Weadb,
         const float* __restrict__ Wa, const float* __restrict__ We,
         u16* __restrict__ Ta, u16* __restrict__ Te)
{
  __shared__ float lst[10];
  const int blk = blockIdx.x;
  if (blk < 512) {
    // ---------------- router ----------------
    if (threadIdx.x < 10) lst[threadIdx.x] = 0.f;
    __syncthreads();
    const int wave = threadIdx.x >> 6, lane = threadIdx.x & 63;
    const float4* wg0 = (const float4*)Wrg;
    const float4* wg1 = (const float4*)(Wrg + 1024);
    const float4* we0 = (const float4*)Wre;
    const float4* we1 = (const float4*)(Wre + 1024);
    const float4* we2 = (const float4*)(Wre + 2048);
    const float4* we3 = (const float4*)(Wre + 3072);
    for (int t = 0; t < 4; t++) {
      const long n = (long)blk * 16 + wave * 4 + t;
      const float4* xr = (const float4*)(x + n * 1024);
      float d0 = 0, d1 = 0, t0 = 0, t1 = 0, t2 = 0, t3 = 0;
      #pragma unroll
      for (int j = 0; j < 4; j++) {
        int id = j * 64 + lane;
        float4 xv = xr[id];
        ushort4 xc;
        xc.x = f2bf_bits(xv.x); xc.y = f2bf_bits(xv.y);
        xc.z = f2bf_bits(xv.z); xc.w = f2bf_bits(xv.w);
        *(ushort4*)(xb + n * 1024 + id * 4) = xc;
        float4 a;
        a = wg0[id]; d0 += xv.x * a.x + xv.y * a.y + xv.z * a.z + xv.w * a.w;
        a = wg1[id]; d1 += xv.x * a.x + xv.y * a.y + xv.z * a.z + xv.w * a.w;
        a = we0[id]; t0 += xv.x * a.x + xv.y * a.y + xv.z * a.z + xv.w * a.w;
        a = we1[id]; t1 += xv.x * a.x + xv.y * a.y + xv.z * a.z + xv.w * a.w;
        a = we2[id]; t2 += xv.x * a.x + xv.y * a.y + xv.z * a.z + xv.w * a.w;
        a = we3[id]; t3 += xv.x * a.x + xv.y * a.y + xv.z * a.z + xv.w * a.w;
      }
      #pragma unroll
      for (int o = 32; o; o >>= 1) {
        d0 += __shfl_xor(d0, o); d1 += __shfl_xor(d1, o);
        t0 += __shfl_xor(t0, o); t1 += __shfl_xor(t1, o);
        t2 += __shfl_xor(t2, o); t3 += __shfl_xor(t3, o);
      }
      if (lane == 0) {
        float mg = fmaxf(d0, d1);
        float e0 = __expf(d0 - mg), e1 = __expf(d1 - mg);
        float invg = 1.f / (e0 + e1);
        float p0 = e0 * invg, p1 = e1 * invg;
        int gi = (d1 > d0) ? 1 : 0;
        float gw = fmaxf(p0, p1);
        float l[4] = {t0, t1, t2, t3};
        float ml = fmaxf(fmaxf(l[0], l[1]), fmaxf(l[2], l[3]));
        float p[4]; float su = 0;
        #pragma unroll
        for (int i = 0; i < 4; i++) { p[i] = __expf(l[i] - ml); su += p[i]; }
        float isu = 1.f / su;
        #pragma unroll
        for (int i = 0; i < 4; i++) p[i] *= isu;
        int i1 = 0;
        #pragma unroll
        for (int i = 1; i < 4; i++) if (p[i] > p[i1]) i1 = i;
        int i2 = (i1 == 0) ? 1 : 0;
        #pragma unroll
        for (int i = 0; i < 4; i++) if (i != i1 && p[i] > p[i2]) i2 = i;
        float s2 = p[i1] + p[i2];
        float invs = 1.f / (s2 + 1e-7f);
        float f1 = gw * p[i1] * invs, f2 = gw * p[i2] * invs;
        int ea = gi * 4 + i1, eb = gi * 4 + i2;
        sumw[n] = f1 + f2;
        fwv[2 * n] = f1; fwv[2 * n + 1] = f2;
        eidxv[2 * n] = ea; eidxv[2 * n + 1] = eb;
        atomicAdd(&lst[ea], f1);
        atomicAdd(&lst[eb], f2);
        atomicAdd(&lst[8], d0 * d0 + d1 * d1);
        atomicAdd(&lst[9], t0 * t0 + t1 * t1 + t2 * t2 + t3 * t3);
      }
    }
    __syncthreads();
    if (threadIdx.x < 10) atomicAdd(&stats[threadIdx.x], lst[threadIdx.x]);
  } else if (blk < 4864) {
    // ---------------- wprep (Wgu packed 32-row-interleaved) ----------------
    long i = ((long)(blk - 512) * 256 + threadIdx.x) * 8;
    const float* s; u16* d; long so, doff;
    if (i < 4194304) {
      long rp = i >> 10, c = i & 1023;
      long i64 = rp >> 6, wi = rp & 63;
      s = (wi < 32) ? Wg : Wu;
      so = (i64 * 32 + (wi & 31)) * 1024 + c;
      d = Wgu; doff = i;
    } else if (i < 6291456) {
      long j = i - 4194304;
      long r = j >> 11, c = j & 2047;
      s = Wd; so = j;
      d = WdQ; doff = r * LDP + c;
    } else if (i < 8388608) { s = Wo;    so = i - 6291456; d = Wob;    doff = so; }
    else if (i < 8650752)   { s = Wpost; so = i - 8388608; d = Wpostb; doff = so; }
    else if (i < 8781824)   { s = Wpre;  so = i - 8650752; d = Wpreb;  doff = so; }
    else                    { s = Wead;  so = i - 8781824; d = Weadb;  doff = so; }
    float4 v0 = *(const float4*)(s + so), v1 = *(const float4*)(s + so + 4);
    ushort4 p, q;
    p.x = f2bf_bits(v0.x); p.y = f2bf_bits(v0.y); p.z = f2bf_bits(v0.z); p.w = f2bf_bits(v0.w);
    q.x = f2bf_bits(v1.x); q.y = f2bf_bits(v1.y); q.z = f2bf_bits(v1.z); q.w = f2bf_bits(v1.w);
    *(ushort4*)(d + doff) = p;
    *(ushort4*)(d + doff + 4) = q;
  } else {
    // ---------------- cvt_t2 ----------------
    int bid = blk - 4864;
    const float* src = (bid < 1024) ? Wa : We;
    u16* dst = (bid < 1024) ? Ta : Te;
    int idx = (bid & 1023) * 256 + threadIdx.x;
    int c = idx >> 11, r = idx & 2047;
    dst[idx] = f2bf_bits(src[(long)r * 128 + c]);
  }
}

// ------- Q reduce: WdQ[:, 2048+c] = sum_s part (M2: c<128 | M1: c>=128) -----
__global__ void reduce_q(const float* __restrict__ part, u16* __restrict__ WdQ)
{
  int idx = blockIdx.x * 256 + threadIdx.x;
  int r = idx >> 8, c = idx & 255;
  const float* p = part + ((c < 128) ? 0 : 524288) + (long)r * 128 + (c & 127);
  float a = p[0] + p[131072] + p[262144] + p[393216];
  WdQ[(long)r * LDP + 2048 + c] = f2bf_bits(a);
}

// ------- row LayerNorm over 128 cols, input = sum of nsplit f32 partials ----
__global__ void __launch_bounds__(256)
ln_rows_part(const float* __restrict__ part, int nsplit,
             const float* __restrict__ g, const float* __restrict__ b,
             const float* __restrict__ sumw,
             u16* __restrict__ out, u16* __restrict__ outT, u16* __restrict__ rawout)
{
  int wave = threadIdx.x >> 6, lane = threadIdx.x & 63;
  long n = (long)blockIdx.x * 4 + wave;
  long base = n * 128;
  float x0 = 0.f, x1 = 0.f;
  for (int s = 0; s < nsplit; s++) {
    x0 += part[(long)s * (N_TOK * ADIM) + base + lane];
    x1 += part[(long)s * (N_TOK * ADIM) + base + 64 + lane];
  }
  if (sumw) { float inv = 1.f / sumw[n]; x0 *= inv; x1 *= inv; }
  float s2 = x0 + x1, q = x0 * x0 + x1 * x1;
  #pragma unroll
  for (int o = 32; o; o >>= 1) { s2 += __shfl_xor(s2, o); q += __shfl_xor(q, o); }
  float m = s2 * (1.f / 128.f);
  float var = q * (1.f / 128.f) - m * m;
  float inv = rsqrtf(var + 1e-5f);
  float y0 = (x0 - m) * inv * g[lane] + b[lane];
  float y1 = (x1 - m) * inv * g[lane + 64] + b[lane + 64];
  out[base + lane] = f2bf_bits(y0);
  out[base + 64 + lane] = f2bf_bits(y1);
  if (outT) {
    long bb = n >> 11, ss = n & 2047;
    outT[(bb * 128 + lane) * 2048 + ss] = f2bf_bits(y0);
    outT[(bb * 128 + lane + 64) * 2048 + ss] = f2bf_bits(y1);
  }
  if (rawout) {
    rawout[base + lane] = f2bf_bits(x0);
    rawout[base + 64 + lane] = f2bf_bits(x1);
  }
}

// ------- P1 reduce: hidP[:, 2048:2176] = 0.1*sumw[n]*sum_s part -------------
__global__ void reduce_part_p1(const float* __restrict__ part,
                               const float* __restrict__ sumw, u16* __restrict__ hidP)
{
  int idx = blockIdx.x * 256 + threadIdx.x;
  int n = idx >> 5, c4 = (idx & 31) * 4;
  int batch = n >> 11, r = n & 2047;
  float4 a = {0.f, 0.f, 0.f, 0.f};
  #pragma unroll
  for (int s = 0; s < 4; s++) {
    float4 v = *(const float4*)(part + (((long)(batch * 4 + s) * 2048 + r) << 7) + c4);
    a.x += v.x; a.y += v.y; a.z += v.z; a.w += v.w;
  }
  float rs = 0.1f * sumw[n];
  ushort4 o;
  o.x = f2bf_bits(rs * a.x); o.y = f2bf_bits(rs * a.y);
  o.z = f2bf_bits(rs * a.z); o.w = f2bf_bits(rs * a.w);
  *(ushort4*)(hidP + (long)n * LDP + 2048 + c4) = o;
}

__global__ void finalize_loss(const float* __restrict__ stats, float* __restrict__ out)
{
  float tot = 0;
  #pragma unroll
  for (int e = 0; e < 8; e++) tot += stats[e];
  float target = tot * 0.125f;
  float lb = 0;
  #pragma unroll
  for (int e = 0; e < 8; e++) { float d = stats[e] - target; lb += d * d; }
  lb *= 0.125f;
  float z = stats[8] * (1.f / (8192.f * 2.f)) + stats[9] * (1.f / (8192.f * 4.f));
  out[0] = 0.001f * (lb + z);
}

// ------- LN + weighted combine of the 2 selected experts' he rows -----------
__global__ void __launch_bounds__(256)
ln_combine(const u16* __restrict__ he, const int* __restrict__ eidxv,
           const float* __restrict__ fwv, const float* __restrict__ g_e,
           const float* __restrict__ b_e, u16* __restrict__ hidP)
{
  const int wave = threadIdx.x >> 6, lane = threadIdx.x & 63;
  const long n = (long)blockIdx.x * 4 + wave;
  float o0 = 0.f, o1 = 0.f;
  #pragma unroll
  for (int k = 0; k < 2; k++) {
    const int e = eidxv[2 * n + k];
    const float w = fwv[2 * n + k];
    const u16* row = he + ((long)e * N_TOK + n) * 128;
    float h0 = bf2f(row[lane]), h1 = bf2f(row[lane + 64]);
    float s = h0 + h1, q = h0 * h0 + h1 * h1;
    #pragma unroll
    for (int o = 32; o; o >>= 1) { s += __shfl_xor(s, o); q += __shfl_xor(q, o); }
    float m = s * (1.f / 128.f);
    float var = q * (1.f / 128.f) - m * m;
    float inv = rsqrtf(var + 1e-5f);
    o0 += w * ((h0 - m) * inv * g_e[e * 128 + lane] + b_e[e * 128 + lane]);
    o1 += w * ((h1 - m) * inv * g_e[e * 128 + lane + 64] + b_e[e * 128 + lane + 64]);
  }
  hidP[n * LDP + 2176 + lane] = f2bf_bits(0.1f * o0);
  hidP[n * LDP + 2176 + 64 + lane] = f2bf_bits(0.1f * o1);
}

// ----------------------------------------------------------------------------
extern "C" void kernel_launch(void* const* d_in, const int* in_sizes, int n_in,
                              void* d_out, int out_size, void* d_ws, size_t ws_size,
                              hipStream_t stream)
{
  (void)in_sizes; (void)n_in; (void)out_size; (void)ws_size;
  const float* x       = (const float*)d_in[0];
  const float* W_up    = (const float*)d_in[1];
  const float* W_gate  = (const float*)d_in[2];
  const float* W_down  = (const float*)d_in[3];
  const float* W_pre   = (const float*)d_in[4];
  const float* W_post  = (const float*)d_in[5];
  const float* g_an    = (const float*)d_in[6];
  const float* b_an    = (const float*)d_in[7];
  const float* W_aproj = (const float*)d_in[8];
  const float* W_ead   = (const float*)d_in[9];
  const float* g_e     = (const float*)d_in[10];
  const float* b_e     = (const float*)d_in[11];
  const float* W_eproj = (const float*)d_in[12];
  const float* W_oproj = (const float*)d_in[13];
  const float* W_rg    = (const float*)d_in[14];
  const float* W_re    = (const float*)d_in[15];
  float* out = (float*)d_out;

  char* base = (char*)d_ws; size_t off = 0;
  auto alloc = [&](size_t bytes) -> void* {
    void* p = base + off; off = (off + bytes + 255) & ~(size_t)255; return p;
  };
  u16*   xb     = (u16*)  alloc((size_t)N_TOK * DIM * 2);
  u16*   Wgu    = (u16*)  alloc((size_t)2 * HID * DIM * 2);       // packed gate|up
  u16*   WdQ    = (u16*)  alloc((size_t)DIM * LDP * 2);           // Wd | M2 | M1
  u16*   Wob    = (u16*)  alloc((size_t)DIM * HID * 2);
  u16*   Wpostb = (u16*)  alloc((size_t)ADIM * HID * 2);
  u16*   Wpreb  = (u16*)  alloc((size_t)ADIM * DIM * 2);
  u16*   WaTb   = (u16*)  alloc((size_t)ADIM * HID * 2);
  u16*   WeTb   = (u16*)  alloc((size_t)ADIM * HID * 2);
  u16*   Weadb  = (u16*)  alloc((size_t)8 * ADIM * ADIM * 2);
  u16*   hidP   = (u16*)  alloc((size_t)N_TOK * LDP * 2);         // scaled hid | P
  u16*   heb    = (u16*)  alloc((size_t)8 * N_TOK * ADIM * 2);
  float* part   = (float*)heb;
  u16*   preb   = (u16*)  alloc((size_t)N_TOK * ADIM * 2);
  u16*   a_in   = (u16*)  alloc((size_t)N_TOK * ADIM * 2);
  u16*   a_inT  = (u16*)  alloc((size_t)N_TOK * ADIM * 2);
  u16*   a_out  = (u16*)  alloc((size_t)N_TOK * ADIM * 2);
  float* sumw   = (float*)alloc((size_t)N_TOK * 4);
  float* fwv    = (float*)alloc((size_t)N_TOK * 2 * 4);
  int*   eidxv  = (int*)  alloc((size_t)N_TOK * 2 * 4);
  float* stats  = (float*)alloc(64);
  // aw (4 x 2048 x 2048 bf16, 33.5 MB) aliases d_out — lifetime (SILU GEMM ->
  // P1 split GEMM) strictly precedes gemm_f32's writes.
  u16* aw = (u16*)d_out;

  hipFuncSetAttribute((const void*)gemm_gu256,
                      hipFuncAttributeMaxDynamicSharedMemorySize, 131072);

  hipMemsetAsync(stats, 0, 64, stream);

  // router | weight-pack | transposes, one launch
  prep_all<<<6912, 256, 0, stream>>>(x, W_rg, W_re, sumw, fwv, eidxv, stats, xb,
                                     W_gate, W_up, W_down, W_oproj, W_post, W_pre,
                                     W_ead, Wgu, WdQ, Wob, Wpostb, Wpreb, Weadb,
                                     W_aproj, W_eproj, WaTb, WeTb);

  // M2 = Wd @ Wa^T, M1 = Wo @ We^T (split-K 4x512, one launch) -> WdQ Q-cols
  gemm_split_q<<<dim3(1, 8, 8), 256, 0, stream>>>(WdQ, WaTb, LDP, Wob, WeTb, HID, part);
  reduce_q<<<1024, 256, 0, stream>>>(part, WdQ);

  // hidP[:, :2048] = sumw * silu(x@Wg^T) * (x@Wu^T)   (256^2, 32x32 MFMA)
  gemm_gu256<<<512, 512, 131072, stream>>>(xb, Wgu, sumw, hidP);

  // pre = x @ W_pre^T : split-K (4 x 256) -> fused LN (+ transposed + raw bf16)
  gemm_split<<<dim3(1, 64, 4), 256, 0, stream>>>(xb, Wpreb, 256, 4, DIM, DIM, 0, 0, part);
  ln_rows_part<<<2048, 256, 0, stream>>>(part, 4, g_an, b_an, nullptr, a_in, a_inT, preb);

  // he[e] = pre @ W_ead[e]^T for all 8 experts (overwrites part arena)
  gemm_bt<EPI_BF16><<<dim3(1, 64, 8), 256, 0, stream>>>(preb, Weadb, ADIM, ADIM, ADIM,
      0, (long)ADIM * ADIM, (long)N_TOK * ADIM, heb, ADIM, 0);
  ln_combine<<<2048, 256, 0, stream>>>(heb, eidxv, fwv, g_e, b_e, hidP);

  // postf = hidden @ W_post^T : split-K (4 x 512), un-scale by sumw in LN
  gemm_split<<<dim3(1, 64, 4), 256, 0, stream>>>(hidP, Wpostb, 512, 4, LDP, HID, 0, 0, part);
  ln_rows_part<<<2048, 256, 0, stream>>>(part, 4, g_an, b_an, sumw, a_out, nullptr, nullptr);

  // aw[b] = silu(clip(a_in_b @ a_out_b^T))  (bf16, aliased onto d_out)
  gemm_bt<EPI_SILU><<<dim3(16, 16, 4), 256, 0, stream>>>(a_in, a_out, ADIM, ADIM, ADIM,
      (long)SEQ * ADIM, (long)SEQ * ADIM, (long)SEQ * SEQ, aw, SEQ, 0);

  // P1 partials: aw_b @ a_inT_b^T, split-K (4 x 512), 4 batches
  gemm_split<<<dim3(1, 16, 16), 256, 0, stream>>>(aw, a_inT, 512, 4, SEQ, SEQ,
      (long)SEQ * SEQ, (long)ADIM * SEQ, part);
  reduce_part_p1<<<1024, 256, 0, stream>>>(part, sumw, hidP);

  // out = hidP @ WdQ^T   (K = 2304)
  gemm_f32<<<dim3(8, 64, 1), 256, 0, stream>>>(hidP, WdQ, out);

  finalize_loss<<<1, 1, 0, stream>>>(stats, out + (size_t)N_TOK * DIM);
}

// Round 10
// 243.431 us; speedup vs baseline: 1.1385x; 1.1385x over previous
//
#include <hip/hip_runtime.h>
#include <hip/hip_bf16.h>

typedef unsigned short u16;
typedef short bf16x8 __attribute__((ext_vector_type(8)));
typedef float f32x4 __attribute__((ext_vector_type(4)));

#define N_TOK 8192
#define DIM   1024
#define HID   2048
#define ADIM  128
#define SEQ   2048
#define LDP   2304   // row stride of hidP / WdQ (2048 + 256)

__device__ __forceinline__ u16 f2bf_bits(float f){
  unsigned u = __float_as_uint(f);
  unsigned r = (u + 0x7fffu + ((u >> 16) & 1u)) >> 16;
  return (u16)r;
}
__device__ __forceinline__ float bf2f(u16 v){ return __uint_as_float((unsigned)v << 16); }
__device__ __forceinline__ float siluf(float x){ return x / (1.f + __expf(-x)); }

__device__ __forceinline__ void gload16(const void* g, void* l){
  __builtin_amdgcn_global_load_lds((const __attribute__((address_space(1))) void*)g,
                                   (__attribute__((address_space(3))) void*)l, 16, 0, 0);
}

#define SB0() __builtin_amdgcn_sched_barrier(0)

// ================= 256^2 8-wave phased GEMM (round-8 verified, 78.0 us) =====
__global__ void __launch_bounds__(512, 2)
gemm_gu256(const u16* __restrict__ X, const u16* __restrict__ Wgu,
           const float* __restrict__ sumw, u16* __restrict__ hidP)
{
  extern __shared__ u16 lds[];
  const int tid = threadIdx.x, w = tid >> 6, lane = tid & 63;
  const int wm = w >> 2, wn = w & 3;
  const int xcd = blockIdx.x & 7, lloc = blockIdx.x >> 3;
  const int bm = (xcd >> 1) * 8 + (lloc & 7);
  const int bn = (xcd & 1) * 8 + (lloc >> 3);
  const long brow = (long)bm * 256, bcol = (long)bn * 256;
  const int frow = lane & 15;
  const int fks = ((lane >> 4) * 8) ^ (((lane >> 1) & 3) << 3);
  const int srow = lane >> 2;
  const int sslot = (((lane & 3) ^ ((lane >> 3) & 3)) * 8);

  f32x4 acc[8][4];
  #pragma unroll
  for (int m = 0; m < 8; m++)
    #pragma unroll
    for (int n = 0; n < 4; n++)
      #pragma unroll
      for (int i = 0; i < 4; i++) acc[m][n][i] = 0.f;

  auto stage = [&](const u16* __restrict__ gbase, long row0, int kt, int kh,
                   int p, int regoff) {
    #pragma unroll
    for (int i = 0; i < 2; i++) {
      const int r = (i * 8 + w) * 16 + srow;
      const u16* g = gbase + (row0 + r) * 1024 + kt * 64 + kh * 32 + sslot;
      u16* l = &lds[p * 32768 + regoff + kh * 8192 + (i * 8 + w) * 512];
      gload16(g, l);
    }
  };

#define AFRAG(mf, kss) (*(const bf16x8*)&lds[p*32768 + (kss)*8192 + (wm*128 + (mf)*16 + frow)*32 + fks])
#define BFRAG(nf, kss) (*(const bf16x8*)&lds[p*32768 + 16384 + (kss)*8192 + (wn*64 + (nf)*16 + frow)*32 + fks])

  stage(X, brow, 0, 0, 0, 0);
  stage(Wgu, bcol, 0, 0, 0, 16384);
  stage(X, brow, 0, 1, 0, 0);
  stage(Wgu, bcol, 0, 1, 0, 16384);
  asm volatile("s_waitcnt vmcnt(4)" ::: "memory");
  __builtin_amdgcn_s_barrier();

  for (int kt = 0; kt < 16; ++kt) {
    const int p = kt & 1, pn = p ^ 1;
    const int ktn = (kt < 15) ? kt + 1 : 15;
    bf16x8 b[4], a[4];

    // ---- P1
    a[0] = AFRAG(0, 0);
    b[0] = BFRAG(0, 0); b[1] = BFRAG(1, 0); b[2] = BFRAG(2, 0); b[3] = BFRAG(3, 0);
    SB0();
    a[1] = AFRAG(1, 0); SB0();
    a[2] = AFRAG(2, 0); SB0();
    a[3] = AFRAG(3, 0);
    stage(X, brow, ktn, 0, pn, 0);
    __builtin_amdgcn_s_barrier();
    asm volatile("s_waitcnt lgkmcnt(3)" ::: "memory"); SB0();
    __builtin_amdgcn_s_setprio(1);
    #pragma unroll
    for (int n = 0; n < 4; n++)
      acc[0][n] = __builtin_amdgcn_mfma_f32_16x16x32_bf16(a[0], b[n], acc[0][n], 0, 0, 0);
    asm volatile("s_waitcnt lgkmcnt(2)" ::: "memory"); SB0();
    #pragma unroll
    for (int n = 0; n < 4; n++)
      acc[1][n] = __builtin_amdgcn_mfma_f32_16x16x32_bf16(a[1], b[n], acc[1][n], 0, 0, 0);
    asm volatile("s_waitcnt lgkmcnt(1)" ::: "memory"); SB0();
    #pragma unroll
    for (int n = 0; n < 4; n++)
      acc[2][n] = __builtin_amdgcn_mfma_f32_16x16x32_bf16(a[2], b[n], acc[2][n], 0, 0, 0);
    asm volatile("s_waitcnt lgkmcnt(0)" ::: "memory"); SB0();
    #pragma unroll
    for (int n = 0; n < 4; n++)
      acc[3][n] = __builtin_amdgcn_mfma_f32_16x16x32_bf16(a[3], b[n], acc[3][n], 0, 0, 0);
    __builtin_amdgcn_s_setprio(0);
    __builtin_amdgcn_s_barrier();

    // ---- P2
    a[0] = AFRAG(4, 0); SB0();
    a[1] = AFRAG(5, 0); SB0();
    a[2] = AFRAG(6, 0); SB0();
    a[3] = AFRAG(7, 0);
    stage(Wgu, bcol, ktn, 0, pn, 16384);
    __builtin_amdgcn_s_barrier();
    asm volatile("s_waitcnt lgkmcnt(3)" ::: "memory"); SB0();
    __builtin_amdgcn_s_setprio(1);
    #pragma unroll
    for (int n = 0; n < 4; n++)
      acc[4][n] = __builtin_amdgcn_mfma_f32_16x16x32_bf16(a[0], b[n], acc[4][n], 0, 0, 0);
    asm volatile("s_waitcnt lgkmcnt(2)" ::: "memory"); SB0();
    #pragma unroll
    for (int n = 0; n < 4; n++)
      acc[5][n] = __builtin_amdgcn_mfma_f32_16x16x32_bf16(a[1], b[n], acc[5][n], 0, 0, 0);
    asm volatile("s_waitcnt lgkmcnt(1)" ::: "memory"); SB0();
    #pragma unroll
    for (int n = 0; n < 4; n++)
      acc[6][n] = __builtin_amdgcn_mfma_f32_16x16x32_bf16(a[2], b[n], acc[6][n], 0, 0, 0);
    asm volatile("s_waitcnt lgkmcnt(0)" ::: "memory"); SB0();
    #pragma unroll
    for (int n = 0; n < 4; n++)
      acc[7][n] = __builtin_amdgcn_mfma_f32_16x16x32_bf16(a[3], b[n], acc[7][n], 0, 0, 0);
    __builtin_amdgcn_s_setprio(0);
    asm volatile("s_waitcnt vmcnt(4)" ::: "memory");
    __builtin_amdgcn_s_barrier();

    // ---- P3
    a[0] = AFRAG(0, 1);
    b[0] = BFRAG(0, 1); b[1] = BFRAG(1, 1); b[2] = BFRAG(2, 1); b[3] = BFRAG(3, 1);
    SB0();
    a[1] = AFRAG(1, 1); SB0();
    a[2] = AFRAG(2, 1); SB0();
    a[3] = AFRAG(3, 1);
    stage(X, brow, ktn, 1, pn, 0);
    __builtin_amdgcn_s_barrier();
    asm volatile("s_waitcnt lgkmcnt(3)" ::: "memory"); SB0();
    __builtin_amdgcn_s_setprio(1);
    #pragma unroll
    for (int n = 0; n < 4; n++)
      acc[0][n] = __builtin_amdgcn_mfma_f32_16x16x32_bf16(a[0], b[n], acc[0][n], 0, 0, 0);
    asm volatile("s_waitcnt lgkmcnt(2)" ::: "memory"); SB0();
    #pragma unroll
    for (int n = 0; n < 4; n++)
      acc[1][n] = __builtin_amdgcn_mfma_f32_16x16x32_bf16(a[1], b[n], acc[1][n], 0, 0, 0);
    asm volatile("s_waitcnt lgkmcnt(1)" ::: "memory"); SB0();
    #pragma unroll
    for (int n = 0; n < 4; n++)
      acc[2][n] = __builtin_amdgcn_mfma_f32_16x16x32_bf16(a[2], b[n], acc[2][n], 0, 0, 0);
    asm volatile("s_waitcnt lgkmcnt(0)" ::: "memory"); SB0();
    #pragma unroll
    for (int n = 0; n < 4; n++)
      acc[3][n] = __builtin_amdgcn_mfma_f32_16x16x32_bf16(a[3], b[n], acc[3][n], 0, 0, 0);
    __builtin_amdgcn_s_setprio(0);
    __builtin_amdgcn_s_barrier();

    // ---- P4
    a[0] = AFRAG(4, 1); SB0();
    a[1] = AFRAG(5, 1); SB0();
    a[2] = AFRAG(6, 1); SB0();
    a[3] = AFRAG(7, 1);
    stage(Wgu, bcol, ktn, 1, pn, 16384);
    __builtin_amdgcn_s_barrier();
    asm volatile("s_waitcnt lgkmcnt(3)" ::: "memory"); SB0();
    __builtin_amdgcn_s_setprio(1);
    #pragma unroll
    for (int n = 0; n < 4; n++)
      acc[4][n] = __builtin_amdgcn_mfma_f32_16x16x32_bf16(a[0], b[n], acc[4][n], 0, 0, 0);
    asm volatile("s_waitcnt lgkmcnt(2)" ::: "memory"); SB0();
    #pragma unroll
    for (int n = 0; n < 4; n++)
      acc[5][n] = __builtin_amdgcn_mfma_f32_16x16x32_bf16(a[1], b[n], acc[5][n], 0, 0, 0);
    asm volatile("s_waitcnt lgkmcnt(1)" ::: "memory"); SB0();
    #pragma unroll
    for (int n = 0; n < 4; n++)
      acc[6][n] = __builtin_amdgcn_mfma_f32_16x16x32_bf16(a[2], b[n], acc[6][n], 0, 0, 0);
    asm volatile("s_waitcnt lgkmcnt(0)" ::: "memory"); SB0();
    #pragma unroll
    for (int n = 0; n < 4; n++)
      acc[7][n] = __builtin_amdgcn_mfma_f32_16x16x32_bf16(a[3], b[n], acc[7][n], 0, 0, 0);
    __builtin_amdgcn_s_setprio(0);
    asm volatile("s_waitcnt vmcnt(4)" ::: "memory");
    __builtin_amdgcn_s_barrier();
  }
#undef AFRAG
#undef BFRAG

  #pragma unroll
  for (int mf = 0; mf < 8; mf++)
    #pragma unroll
    for (int i = 0; i < 4; i++) {
      const long r = brow + wm * 128 + mf * 16 + (lane >> 4) * 4 + i;
      const float sw = sumw[r];
      #pragma unroll
      for (int q = 0; q < 2; q++) {
        const float g = acc[mf][2 * q][i], u = acc[mf][2 * q + 1][i];
        const int hcol = (bn * 8 + wn * 2 + q) * 16 + (lane & 15);
        hidP[r * LDP + hcol] = f2bf_bits(sw * (siluf(g) * u));
      }
    }
}

// ------------- shared 128^2 K-loop (BK=32, swizzled) ------------------------
__device__ __forceinline__ void kloop128(const u16* __restrict__ A, const u16* __restrict__ B,
                                         int lda, int ldb, int K,
                                         u16* lA, u16* lB, f32x4 (&acc)[4][4])
{
  const int tid = threadIdx.x, wave = tid >> 6, lane = tid & 63;
  const int wr = (wave >> 1) * 64, wc = (wave & 1) * 64;
  const int sr = tid >> 2, sks = ((tid & 3) ^ ((tid >> 3) & 3)) * 8;
  const u16* gA = A + (long)sr * lda + sks;
  const u16* gB = B + (long)sr * ldb + sks;
  const long rA = (long)64 * lda, rB = (long)64 * ldb;
  u16* lA0 = &lA[wave * 512]; u16* lA1 = &lA[2048 + wave * 512];
  u16* lB0 = &lB[wave * 512]; u16* lB1 = &lB[2048 + wave * 512];
  const int frow = lane & 15;
  const int fks = ((lane >> 4) * 8) ^ (((lane >> 1) & 3) << 3);

  for (int kt = 0; kt < K; kt += 32) {
    gload16(gA, lA0); gload16(gA + rA, lA1);
    gload16(gB, lB0); gload16(gB + rB, lB1);
    gA += 32; gB += 32;
    asm volatile("s_waitcnt vmcnt(0)" ::: "memory");
    __syncthreads();
    bf16x8 af[4], bfv[4];
    #pragma unroll
    for (int m = 0; m < 4; m++) af[m] = *(const bf16x8*)&lA[(wr + m * 16 + frow) * 32 + fks];
    #pragma unroll
    for (int n = 0; n < 4; n++) bfv[n] = *(const bf16x8*)&lB[(wc + n * 16 + frow) * 32 + fks];
    #pragma unroll
    for (int m = 0; m < 4; m++)
      #pragma unroll
      for (int n = 0; n < 4; n++)
        acc[m][n] = __builtin_amdgcn_mfma_f32_16x16x32_bf16(af[m], bfv[n], acc[m][n], 0, 0, 0);
    __syncthreads();
  }
}

__device__ __forceinline__ void acc_zero(f32x4 (&acc)[4][4]){
  #pragma unroll
  for (int m = 0; m < 4; m++)
    #pragma unroll
    for (int n = 0; n < 4; n++)
      #pragma unroll
      for (int i = 0; i < 4; i++) acc[m][n][i] = 0.f;
}

// ---------------- SILU score GEMM (standalone): aw = silu(clip(.)) ----------
__global__ void __launch_bounds__(256, 2)
gemm_silu(const u16* __restrict__ Ag, const u16* __restrict__ Bg,
          u16* __restrict__ bout)
{
  __shared__ u16 lA[4096];
  __shared__ u16 lB[4096];
  const int wave = threadIdx.x >> 6, lane = threadIdx.x & 63;
  const long brow = (long)blockIdx.y * 128, bcol = (long)blockIdx.x * 128;
  const u16* A = Ag + (long)blockIdx.z * (SEQ * ADIM) + brow * ADIM;
  const u16* B = Bg + (long)blockIdx.z * (SEQ * ADIM) + bcol * ADIM;
  f32x4 acc[4][4]; acc_zero(acc);
  kloop128(A, B, ADIM, ADIM, ADIM, lA, lB, acc);
  const int wr = (wave >> 1) * 64, wc = (wave & 1) * 64;
  const long r0 = brow + wr + ((lane >> 4) << 2);
  const long c0 = bcol + wc + (lane & 15);
  u16* O = bout + (long)blockIdx.z * ((long)SEQ * SEQ);
  #pragma unroll
  for (int m = 0; m < 4; m++)
    #pragma unroll
    for (int i = 0; i < 4; i++) {
      long r = r0 + m * 16 + i;
      #pragma unroll
      for (int n = 0; n < 4; n++) {
        float v = acc[m][n][i];
        v = fminf(5.f, fmaxf(-5.f, v));
        O[r * SEQ + c0 + n * 16] = f2bf_bits(siluf(v));
      }
    }
}

// ------------- P1 split-K partial GEMM (standalone) -------------------------
__global__ void __launch_bounds__(256, 2)
gemm_split_p1(const u16* __restrict__ aw, const u16* __restrict__ a_inT,
              float* __restrict__ part)
{
  __shared__ u16 lA[4096];
  __shared__ u16 lB[4096];
  const int wave = threadIdx.x >> 6, lane = threadIdx.x & 63;
  const int z = blockIdx.z, batch = z >> 2, split = z & 3;
  const long brow = (long)blockIdx.y * 128;
  const u16* A = aw + (long)batch * SEQ * SEQ + brow * SEQ + (long)split * 512;
  const u16* B = a_inT + (long)batch * ADIM * SEQ + (long)split * 512;
  f32x4 acc[4][4]; acc_zero(acc);
  kloop128(A, B, SEQ, SEQ, 512, lA, lB, acc);
  float* po = part + (long)z * (SEQ * ADIM);
  const int wr = (wave >> 1) * 64, wc = (wave & 1) * 64;
  const long rr = brow + wr + ((lane >> 4) << 2);
  const int cc = wc + (lane & 15);
  #pragma unroll
  for (int m = 0; m < 4; m++)
    #pragma unroll
    for (int i = 0; i < 4; i++) {
      long r = rr + m * 16 + i;
      #pragma unroll
      for (int n = 0; n < 4; n++)
        po[r * 128 + cc + n * 16] = acc[m][n][i];
    }
}

// ------ merged: pre-split (blk<256) | M1/M2-split (blk 256-319) -------------
__global__ void __launch_bounds__(256, 2)
split_pq(const u16* __restrict__ xb, const u16* __restrict__ Wpreb,
         const u16* __restrict__ WdQ, const u16* __restrict__ WaTb,
         const u16* __restrict__ Wob, const u16* __restrict__ WeTb,
         float* __restrict__ part, float* __restrict__ qpart)
{
  __shared__ u16 lA[4096];
  __shared__ u16 lB[4096];
  const int blk = blockIdx.x;
  const int wave = threadIdx.x >> 6, lane = threadIdx.x & 63;
  f32x4 acc[4][4]; acc_zero(acc);
  const int wr = (wave >> 1) * 64, wc = (wave & 1) * 64;

  if (blk < 256) {
    // pre = xb @ Wpreb^T, split-K 4 x 256
    const int y = blk & 63, z = blk >> 6;
    const long brow = (long)y * 128;
    const u16* A = xb + brow * DIM + (long)z * 256;
    const u16* B = Wpreb + (long)z * 256;
    kloop128(A, B, DIM, DIM, 256, lA, lB, acc);
    float* po = part + (long)z * (N_TOK * ADIM);
    const long rr = brow + wr + ((lane >> 4) << 2);
    const int cc = wc + (lane & 15);
    #pragma unroll
    for (int m = 0; m < 4; m++)
      #pragma unroll
      for (int i = 0; i < 4; i++) {
        long r = rr + m * 16 + i;
        #pragma unroll
        for (int n = 0; n < 4; n++)
          po[r * 128 + cc + n * 16] = acc[m][n][i];
      }
  } else {
    // q: z<4 -> WdQ@WaTb^T, z>=4 -> Wob@WeTb^T, split-K 4 x 512
    const int q = blk - 256;            // 0..63
    const int y = q & 7, z = q >> 3;    // y row-tile, z job*split
    const int sel = z >> 2, split = z & 3;
    const long brow = (long)y * 128;
    const int lda = sel ? HID : LDP;
    const u16* A = (sel ? Wob : WdQ) + brow * lda + (long)split * 512;
    const u16* B = (sel ? WeTb : WaTb) + (long)split * 512;
    kloop128(A, B, lda, HID, 512, lA, lB, acc);
    float* po = qpart + (long)z * 131072;
    const long rr = brow + wr + ((lane >> 4) << 2);
    const int cc = wc + (lane & 15);
    #pragma unroll
    for (int m = 0; m < 4; m++)
      #pragma unroll
      for (int i = 0; i < 4; i++) {
        long r = rr + m * 16 + i;
        #pragma unroll
        for (int n = 0; n < 4; n++)
          po[r * 128 + cc + n * 16] = acc[m][n][i];
      }
  }
}

// ------ merged: he-GEMM (blk<512) | postf-split (blk 512-767) ---------------
__global__ void __launch_bounds__(256, 2)
he_postf(const u16* __restrict__ preb, const u16* __restrict__ Weadb,
         u16* __restrict__ heb, const u16* __restrict__ hidP,
         const u16* __restrict__ Wpostb, float* __restrict__ postfp)
{
  __shared__ u16 lA[4096];
  __shared__ u16 lB[4096];
  const int blk = blockIdx.x;
  const int wave = threadIdx.x >> 6, lane = threadIdx.x & 63;
  f32x4 acc[4][4]; acc_zero(acc);
  const int wr = (wave >> 1) * 64, wc = (wave & 1) * 64;

  if (blk < 512) {
    // he[e] = preb @ Wead[e]^T, K=128
    const int y = blk & 63, e = blk >> 6;
    const long brow = (long)y * 128;
    const u16* A = preb + brow * ADIM;
    const u16* B = Weadb + (long)e * ADIM * ADIM;
    kloop128(A, B, ADIM, ADIM, ADIM, lA, lB, acc);
    u16* O = heb + (long)e * N_TOK * ADIM;
    const long r0 = brow + wr + ((lane >> 4) << 2);
    const long c0 = wc + (lane & 15);
    #pragma unroll
    for (int m = 0; m < 4; m++)
      #pragma unroll
      for (int i = 0; i < 4; i++) {
        long r = r0 + m * 16 + i;
        #pragma unroll
        for (int n = 0; n < 4; n++)
          O[r * ADIM + c0 + n * 16] = f2bf_bits(acc[m][n][i]);
      }
  } else {
    // postf = hidP[:, :2048] @ Wpost^T, split-K 4 x 512
    const int q = blk - 512;
    const int y = q & 63, z = q >> 6;
    const long brow = (long)y * 128;
    const u16* A = hidP + brow * LDP + (long)z * 512;
    const u16* B = Wpostb + (long)z * 512;
    kloop128(A, B, LDP, HID, 512, lA, lB, acc);
    float* po = postfp + (long)z * (N_TOK * ADIM);
    const long rr = brow + wr + ((lane >> 4) << 2);
    const int cc = wc + (lane & 15);
    #pragma unroll
    for (int m = 0; m < 4; m++)
      #pragma unroll
      for (int i = 0; i < 4; i++) {
        long r = rr + m * 16 + i;
        #pragma unroll
        for (int n = 0; n < 4; n++)
          po[r * 128 + cc + n * 16] = acc[m][n][i];
      }
  }
}

// ---------------- final out = hidP @ WdQ^T (K=2304) + loss ------------------
__global__ void __launch_bounds__(256, 2)
gemm_f32(const u16* __restrict__ Ag, const u16* __restrict__ Bg,
         const float* __restrict__ stats, float* __restrict__ out)
{
  __shared__ u16 lA[4096];
  __shared__ u16 lB[4096];
  const int wave = threadIdx.x >> 6, lane = threadIdx.x & 63;
  const long brow = (long)blockIdx.y * 128, bcol = (long)blockIdx.x * 128;
  f32x4 acc[4][4]; acc_zero(acc);
  kloop128(Ag + brow * LDP, Bg + bcol * LDP, LDP, LDP, LDP, lA, lB, acc);
  const int wr = (wave >> 1) * 64, wc = (wave & 1) * 64;
  const long r0 = brow + wr + ((lane >> 4) << 2);
  const long c0 = bcol + wc + (lane & 15);
  #pragma unroll
  for (int m = 0; m < 4; m++)
    #pragma unroll
    for (int i = 0; i < 4; i++) {
      long r = r0 + m * 16 + i;
      #pragma unroll
      for (int n = 0; n < 4; n++)
        out[r * DIM + c0 + n * 16] = acc[m][n][i];
    }
  if (blockIdx.x == 0 && blockIdx.y == 0 && threadIdx.x == 0) {
    float tot = 0;
    #pragma unroll
    for (int e = 0; e < 8; e++) tot += stats[e];
    float target = tot * 0.125f;
    float lb = 0;
    #pragma unroll
    for (int e = 0; e < 8; e++) { float d = stats[e] - target; lb += d * d; }
    lb *= 0.125f;
    float z = stats[8] * (1.f / (8192.f * 2.f)) + stats[9] * (1.f / (8192.f * 4.f));
    out[(size_t)N_TOK * DIM] = 0.001f * (lb + z);
  }
}

// ======== merged prep: router | wprep | cvt_t2 (round-8 verified) ===========
__global__ void __launch_bounds__(256)
prep_all(const float* __restrict__ x, const float* __restrict__ Wrg,
         const float* __restrict__ Wre, float* __restrict__ sumw,
         float* __restrict__ fwv, int* __restrict__ eidxv,
         float* __restrict__ stats, u16* __restrict__ xb,
         const float* __restrict__ Wg, const float* __restrict__ Wu,
         const float* __restrict__ Wd, const float* __restrict__ Wo,
         const float* __restrict__ Wpost, const float* __restrict__ Wpre,
         const float* __restrict__ Wead,
         u16* __restrict__ Wgu, u16* __restrict__ WdQ,
         u16* __restrict__ Wob, u16* __restrict__ Wpostb,
         u16* __restrict__ Wpreb, u16* __restrict__ Weadb,
         const float* __restrict__ Wa, const float* __restrict__ We,
         u16* __restrict__ Ta, u16* __restrict__ Te)
{
  __shared__ float lst[10];
  const int blk = blockIdx.x;
  if (blk < 512) {
    if (threadIdx.x < 10) lst[threadIdx.x] = 0.f;
    __syncthreads();
    const int wave = threadIdx.x >> 6, lane = threadIdx.x & 63;
    const float4* wg0 = (const float4*)Wrg;
    const float4* wg1 = (const float4*)(Wrg + 1024);
    const float4* we0 = (const float4*)Wre;
    const float4* we1 = (const float4*)(Wre + 1024);
    const float4* we2 = (const float4*)(Wre + 2048);
    const float4* we3 = (const float4*)(Wre + 3072);
    for (int t = 0; t < 4; t++) {
      const long n = (long)blk * 16 + wave * 4 + t;
      const float4* xr = (const float4*)(x + n * 1024);
      float d0 = 0, d1 = 0, t0 = 0, t1 = 0, t2 = 0, t3 = 0;
      #pragma unroll
      for (int j = 0; j < 4; j++) {
        int id = j * 64 + lane;
        float4 xv = xr[id];
        ushort4 xc;
        xc.x = f2bf_bits(xv.x); xc.y = f2bf_bits(xv.y);
        xc.z = f2bf_bits(xv.z); xc.w = f2bf_bits(xv.w);
        *(ushort4*)(xb + n * 1024 + id * 4) = xc;
        float4 a;
        a = wg0[id]; d0 += xv.x * a.x + xv.y * a.y + xv.z * a.z + xv.w * a.w;
        a = wg1[id]; d1 += xv.x * a.x + xv.y * a.y + xv.z * a.z + xv.w * a.w;
        a = we0[id]; t0 += xv.x * a.x + xv.y * a.y + xv.z * a.z + xv.w * a.w;
        a = we1[id]; t1 += xv.x * a.x + xv.y * a.y + xv.z * a.z + xv.w * a.w;
        a = we2[id]; t2 += xv.x * a.x + xv.y * a.y + xv.z * a.z + xv.w * a.w;
        a = we3[id]; t3 += xv.x * a.x + xv.y * a.y + xv.z * a.z + xv.w * a.w;
      }
      #pragma unroll
      for (int o = 32; o; o >>= 1) {
        d0 += __shfl_xor(d0, o); d1 += __shfl_xor(d1, o);
        t0 += __shfl_xor(t0, o); t1 += __shfl_xor(t1, o);
        t2 += __shfl_xor(t2, o); t3 += __shfl_xor(t3, o);
      }
      if (lane == 0) {
        float mg = fmaxf(d0, d1);
        float e0 = __expf(d0 - mg), e1 = __expf(d1 - mg);
        float invg = 1.f / (e0 + e1);
        float p0 = e0 * invg, p1 = e1 * invg;
        int gi = (d1 > d0) ? 1 : 0;
        float gw = fmaxf(p0, p1);
        float l[4] = {t0, t1, t2, t3};
        float ml = fmaxf(fmaxf(l[0], l[1]), fmaxf(l[2], l[3]));
        float p[4]; float su = 0;
        #pragma unroll
        for (int i = 0; i < 4; i++) { p[i] = __expf(l[i] - ml); su += p[i]; }
        float isu = 1.f / su;
        #pragma unroll
        for (int i = 0; i < 4; i++) p[i] *= isu;
        int i1 = 0;
        #pragma unroll
        for (int i = 1; i < 4; i++) if (p[i] > p[i1]) i1 = i;
        int i2 = (i1 == 0) ? 1 : 0;
        #pragma unroll
        for (int i = 0; i < 4; i++) if (i != i1 && p[i] > p[i2]) i2 = i;
        float s2 = p[i1] + p[i2];
        float invs = 1.f / (s2 + 1e-7f);
        float f1 = gw * p[i1] * invs, f2 = gw * p[i2] * invs;
        int ea = gi * 4 + i1, eb = gi * 4 + i2;
        sumw[n] = f1 + f2;
        fwv[2 * n] = f1; fwv[2 * n + 1] = f2;
        eidxv[2 * n] = ea; eidxv[2 * n + 1] = eb;
        atomicAdd(&lst[ea], f1);
        atomicAdd(&lst[eb], f2);
        atomicAdd(&lst[8], d0 * d0 + d1 * d1);
        atomicAdd(&lst[9], t0 * t0 + t1 * t1 + t2 * t2 + t3 * t3);
      }
    }
    __syncthreads();
    if (threadIdx.x < 10) atomicAdd(&stats[threadIdx.x], lst[threadIdx.x]);
  } else if (blk < 4864) {
    long i = ((long)(blk - 512) * 256 + threadIdx.x) * 8;
    const float* s; u16* d; long so, doff;
    if (i < 4194304) {                  // Wgu pack (16-row interleave)
      long rp = i >> 10, c = i & 1023;
      long i32 = rp >> 5, wi = rp & 31;
      s = (wi < 16) ? Wg : Wu;
      so = (i32 * 16 + (wi & 15)) * 1024 + c;
      d = Wgu; doff = i;
    } else if (i < 6291456) {
      long j = i - 4194304;
      long r = j >> 11, c = j & 2047;
      s = Wd; so = j;
      d = WdQ; doff = r * LDP + c;
    } else if (i < 8388608) { s = Wo;    so = i - 6291456; d = Wob;    doff = so; }
    else if (i < 8650752)   { s = Wpost; so = i - 8388608; d = Wpostb; doff = so; }
    else if (i < 8781824)   { s = Wpre;  so = i - 8650752; d = Wpreb;  doff = so; }
    else                    { s = Wead;  so = i - 8781824; d = Weadb;  doff = so; }
    float4 v0 = *(const float4*)(s + so), v1 = *(const float4*)(s + so + 4);
    ushort4 p, q;
    p.x = f2bf_bits(v0.x); p.y = f2bf_bits(v0.y); p.z = f2bf_bits(v0.z); p.w = f2bf_bits(v0.w);
    q.x = f2bf_bits(v1.x); q.y = f2bf_bits(v1.y); q.z = f2bf_bits(v1.z); q.w = f2bf_bits(v1.w);
    *(ushort4*)(d + doff) = p;
    *(ushort4*)(d + doff + 4) = q;
  } else {
    int bid = blk - 4864;
    const float* src = (bid < 1024) ? Wa : We;
    u16* dst = (bid < 1024) ? Ta : Te;
    int idx = (bid & 1023) * 256 + threadIdx.x;
    int c = idx >> 11, r = idx & 2047;
    dst[idx] = f2bf_bits(src[(long)r * 128 + c]);
  }
}

// ------ merged: ln_rows(pre) (blk<2048) | reduce_q (blk 2048-3071) ----------
__global__ void __launch_bounds__(256)
ln1_rq(const float* __restrict__ part, const float* __restrict__ qpart,
       const float* __restrict__ g, const float* __restrict__ b,
       u16* __restrict__ a_in, u16* __restrict__ a_inT, u16* __restrict__ preb,
       u16* __restrict__ WdQ)
{
  const int blk = blockIdx.x;
  if (blk < 2048) {
    int wave = threadIdx.x >> 6, lane = threadIdx.x & 63;
    long n = (long)blk * 4 + wave;
    long base = n * 128;
    float x0 = 0.f, x1 = 0.f;
    #pragma unroll
    for (int s = 0; s < 4; s++) {
      x0 += part[(long)s * (N_TOK * ADIM) + base + lane];
      x1 += part[(long)s * (N_TOK * ADIM) + base + 64 + lane];
    }
    float s2 = x0 + x1, q = x0 * x0 + x1 * x1;
    #pragma unroll
    for (int o = 32; o; o >>= 1) { s2 += __shfl_xor(s2, o); q += __shfl_xor(q, o); }
    float m = s2 * (1.f / 128.f);
    float var = q * (1.f / 128.f) - m * m;
    float inv = rsqrtf(var + 1e-5f);
    float y0 = (x0 - m) * inv * g[lane] + b[lane];
    float y1 = (x1 - m) * inv * g[lane + 64] + b[lane + 64];
    a_in[base + lane] = f2bf_bits(y0);
    a_in[base + 64 + lane] = f2bf_bits(y1);
    long bb = n >> 11, ss = n & 2047;
    a_inT[(bb * 128 + lane) * 2048 + ss] = f2bf_bits(y0);
    a_inT[(bb * 128 + lane + 64) * 2048 + ss] = f2bf_bits(y1);
    preb[base + lane] = f2bf_bits(x0);
    preb[base + 64 + lane] = f2bf_bits(x1);
  } else {
    int idx = (blk - 2048) * 256 + threadIdx.x;   // 262144 = 1024 rows x 256 cols
    int r = idx >> 8, c = idx & 255;
    const float* p = qpart + ((c < 128) ? 0 : 524288) + (long)r * 128 + (c & 127);
    float a = p[0] + p[131072] + p[262144] + p[393216];
    WdQ[(long)r * LDP + 2048 + c] = f2bf_bits(a);
  }
}

// ------ merged: ln_combine (blk<2048) | ln_rows(postf) (blk 2048-4095) ------
__global__ void __launch_bounds__(256)
lnc_ln2(const u16* __restrict__ heb, const int* __restrict__ eidxv,
        const float* __restrict__ fwv, const float* __restrict__ g_e,
        const float* __restrict__ b_e, u16* __restrict__ hidP,
        const float* __restrict__ postfp, const float* __restrict__ g_an,
        const float* __restrict__ b_an, const float* __restrict__ sumw,
        u16* __restrict__ a_out)
{
  const int blk = blockIdx.x;
  const int wave = threadIdx.x >> 6, lane = threadIdx.x & 63;
  if (blk < 2048) {
    const long n = (long)blk * 4 + wave;
    float o0 = 0.f, o1 = 0.f;
    #pragma unroll
    for (int k = 0; k < 2; k++) {
      const int e = eidxv[2 * n + k];
      const float w = fwv[2 * n + k];
      const u16* row = heb + ((long)e * N_TOK + n) * 128;
      float h0 = bf2f(row[lane]), h1 = bf2f(row[lane + 64]);
      float s = h0 + h1, q = h0 * h0 + h1 * h1;
      #pragma unroll
      for (int o = 32; o; o >>= 1) { s += __shfl_xor(s, o); q += __shfl_xor(q, o); }
      float m = s * (1.f / 128.f);
      float var = q * (1.f / 128.f) - m * m;
      float inv = rsqrtf(var + 1e-5f);
      o0 += w * ((h0 - m) * inv * g_e[e * 128 + lane] + b_e[e * 128 + lane]);
      o1 += w * ((h1 - m) * inv * g_e[e * 128 + lane + 64] + b_e[e * 128 + lane + 64]);
    }
    hidP[n * LDP + 2176 + lane] = f2bf_bits(0.1f * o0);
    hidP[n * LDP + 2176 + 64 + lane] = f2bf_bits(0.1f * o1);
  } else {
    long n = (long)(blk - 2048) * 4 + wave;
    long base = n * 128;
    float x0 = 0.f, x1 = 0.f;
    #pragma unroll
    for (int s = 0; s < 4; s++) {
      x0 += postfp[(long)s * (N_TOK * ADIM) + base + lane];
      x1 += postfp[(long)s * (N_TOK * ADIM) + base + 64 + lane];
    }
    float invw = 1.f / sumw[n]; x0 *= invw; x1 *= invw;
    float s2 = x0 + x1, q = x0 * x0 + x1 * x1;
    #pragma unroll
    for (int o = 32; o; o >>= 1) { s2 += __shfl_xor(s2, o); q += __shfl_xor(q, o); }
    float m = s2 * (1.f / 128.f);
    float var = q * (1.f / 128.f) - m * m;
    float inv = rsqrtf(var + 1e-5f);
    a_out[base + lane] = f2bf_bits((x0 - m) * inv * g_an[lane] + b_an[lane]);
    a_out[base + 64 + lane] = f2bf_bits((x1 - m) * inv * g_an[lane + 64] + b_an[lane + 64]);
  }
}

// ------- P1 reduce: hidP[:, 2048:2176] = 0.1*sumw[n]*sum_s part -------------
__global__ void reduce_part_p1(const float* __restrict__ part,
                               const float* __restrict__ sumw, u16* __restrict__ hidP)
{
  int idx = blockIdx.x * 256 + threadIdx.x;
  int n = idx >> 5, c4 = (idx & 31) * 4;
  int batch = n >> 11, r = n & 2047;
  float4 a = {0.f, 0.f, 0.f, 0.f};
  #pragma unroll
  for (int s = 0; s < 4; s++) {
    float4 v = *(const float4*)(part + (((long)(batch * 4 + s) * 2048 + r) << 7) + c4);
    a.x += v.x; a.y += v.y; a.z += v.z; a.w += v.w;
  }
  float rs = 0.1f * sumw[n];
  ushort4 o;
  o.x = f2bf_bits(rs * a.x); o.y = f2bf_bits(rs * a.y);
  o.z = f2bf_bits(rs * a.z); o.w = f2bf_bits(rs * a.w);
  *(ushort4*)(hidP + (long)n * LDP + 2048 + c4) = o;
}

// ----------------------------------------------------------------------------
extern "C" void kernel_launch(void* const* d_in, const int* in_sizes, int n_in,
                              void* d_out, int out_size, void* d_ws, size_t ws_size,
                              hipStream_t stream)
{
  (void)in_sizes; (void)n_in; (void)out_size; (void)ws_size;
  const float* x       = (const float*)d_in[0];
  const float* W_up    = (const float*)d_in[1];
  const float* W_gate  = (const float*)d_in[2];
  const float* W_down  = (const float*)d_in[3];
  const float* W_pre   = (const float*)d_in[4];
  const float* W_post  = (const float*)d_in[5];
  const float* g_an    = (const float*)d_in[6];
  const float* b_an    = (const float*)d_in[7];
  const float* W_aproj = (const float*)d_in[8];
  const float* W_ead   = (const float*)d_in[9];
  const float* g_e     = (const float*)d_in[10];
  const float* b_e     = (const float*)d_in[11];
  const float* W_eproj = (const float*)d_in[12];
  const float* W_oproj = (const float*)d_in[13];
  const float* W_rg    = (const float*)d_in[14];
  const float* W_re    = (const float*)d_in[15];
  float* out = (float*)d_out;

  char* base = (char*)d_ws; size_t off = 0;
  auto alloc = [&](size_t bytes) -> void* {
    void* p = base + off; off = (off + bytes + 255) & ~(size_t)255; return p;
  };
  u16*   xb     = (u16*)  alloc((size_t)N_TOK * DIM * 2);
  u16*   Wgu    = (u16*)  alloc((size_t)2 * HID * DIM * 2);       // packed gate|up
  u16*   WdQ    = (u16*)  alloc((size_t)DIM * LDP * 2);           // Wd | M2 | M1
  u16*   Wob    = (u16*)  alloc((size_t)DIM * HID * 2);
  u16*   Wpostb = (u16*)  alloc((size_t)ADIM * HID * 2);
  u16*   Wpreb  = (u16*)  alloc((size_t)ADIM * DIM * 2);
  u16*   WaTb   = (u16*)  alloc((size_t)ADIM * HID * 2);
  u16*   WeTb   = (u16*)  alloc((size_t)ADIM * HID * 2);
  u16*   Weadb  = (u16*)  alloc((size_t)8 * ADIM * ADIM * 2);
  u16*   hidP   = (u16*)  alloc((size_t)N_TOK * LDP * 2);         // scaled hid | P
  u16*   heb    = (u16*)  alloc((size_t)8 * N_TOK * ADIM * 2);    // also part arena
  float* part   = (float*)heb;
  u16*   preb   = (u16*)  alloc((size_t)N_TOK * ADIM * 2);
  u16*   a_in   = (u16*)  alloc((size_t)N_TOK * ADIM * 2);
  u16*   a_inT  = (u16*)  alloc((size_t)N_TOK * ADIM * 2);
  u16*   a_out  = (u16*)  alloc((size_t)N_TOK * ADIM * 2);
  float* sumw   = (float*)alloc((size_t)N_TOK * 4);
  float* fwv    = (float*)alloc((size_t)N_TOK * 2 * 4);
  int*   eidxv  = (int*)  alloc((size_t)N_TOK * 2 * 4);
  float* stats  = (float*)alloc(64);
  // d_out (33.5 MB) time-shared as scratch, all strictly before gemm_f32:
  //  - postfp (16.8 MB f32 postf partials): he_postf -> lnc_ln2
  //  - qpart  (4.2 MB f32 M1/M2 partials, at +16.8MB): split_pq -> ln1_rq
  //  - aw     (33.5 MB bf16 scores): gemm_silu -> gemm_split_p1
  float* postfp = (float*)d_out;
  float* qpart  = (float*)((char*)d_out + 16777216);
  u16*   aw     = (u16*)d_out;

  hipFuncSetAttribute((const void*)gemm_gu256,
                      hipFuncAttributeMaxDynamicSharedMemorySize, 131072);

  hipMemsetAsync(stats, 0, 64, stream);

  // 1. router | weight-pack | transposes
  prep_all<<<6912, 256, 0, stream>>>(x, W_rg, W_re, sumw, fwv, eidxv, stats, xb,
                                     W_gate, W_up, W_down, W_oproj, W_post, W_pre,
                                     W_ead, Wgu, WdQ, Wob, Wpostb, Wpreb, Weadb,
                                     W_aproj, W_eproj, WaTb, WeTb);

  // 2. hidP[:, :2048] = sumw * silu(x@Wg^T) * (x@Wu^T)
  gemm_gu256<<<512, 512, 131072, stream>>>(xb, Wgu, sumw, hidP);

  // 3. pre-split (part) | M1/M2-split (qpart)
  split_pq<<<320, 256, 0, stream>>>(xb, Wpreb, WdQ, WaTb, Wob, WeTb, part, qpart);

  // 4. LN(pre) -> a_in/a_inT/preb | reduce qpart -> WdQ Q-cols
  ln1_rq<<<3072, 256, 0, stream>>>(part, qpart, g_an, b_an, a_in, a_inT, preb, WdQ);

  // 5. he[e] = preb @ Wead[e]^T -> heb | postf-split -> postfp
  he_postf<<<768, 256, 0, stream>>>(preb, Weadb, heb, hidP, Wpostb, postfp);

  // 6. expert LN+combine -> hidP[:,2176:] | LN(postf/sumw) -> a_out
  lnc_ln2<<<4096, 256, 0, stream>>>(heb, eidxv, fwv, g_e, b_e, hidP,
                                    postfp, g_an, b_an, sumw, a_out);

  // 7. aw[b] = silu(clip(a_in_b @ a_out_b^T))
  gemm_silu<<<dim3(16, 16, 4), 256, 0, stream>>>(a_in, a_out, aw);

  // 8. P1 partials: aw_b @ a_inT_b^T, split-K 4x512
  gemm_split_p1<<<dim3(1, 16, 16), 256, 0, stream>>>(aw, a_inT, part);

  // 9. reduce -> hidP[:, 2048:2176]
  reduce_part_p1<<<1024, 256, 0, stream>>>(part, sumw, hidP);

  // 10. out = hidP @ WdQ^T (K=2304) + router loss
  gemm_f32<<<dim3(8, 64, 1), 256, 0, stream>>>(hidP, WdQ, stats, out);
}